// Round 16
// baseline (19.343 us; speedup 1.0000x reference)
//
#include <hip/hip_runtime.h>
#include <stdint.h>

// Shapes fixed by setup_inputs: B=4, D=20, H=W=128, HW=16384, 1024 tiles of 64 voxels.
// R16 = R15 with the wave decomposition re-balanced to 4 waves of 10x10:
//  - wave (ri,cj in {0,1}) owns rows ri*10..+9 x cols cj*10..+9. Load redundancy
//    drops from {pred 4x, gt 2x} to exactly 2x everywhere: 280 load-instrs/block
//    vs R15's 403. DS-atomics 5376/tile vs 8192.
//  - 256-thread blocks, launch_bounds(256,6): VGPR cap 85 (live ~60, no spill --
//    R12 proved forcing <=64 spills; 85 is the proven-safe regime). 1024 blocks
//    x 4 waves -> 4 blocks/CU needed for full residency, 6 schedulable -> NO tail.
//  - publish cmask bits before hot loop; branch-free sel (R15-proven exact).
//  - per-block record stores + separate fin kernel (R7-proven, uncontended).
#define HW     16384
#define NTILES 1024
#define INFI   0x7f800000

__global__ __launch_bounds__(256, 6) void chamfer_main(
    const float* __restrict__ pred,   // [B, 60, HW]  channel c*20+i
    const float* __restrict__ gt,     // [B, 60, HW]  channel j*3+c
    const float* __restrict__ cmask,  // [B, 20, HW]
    const float* __restrict__ vmask,  // [B, HW]
    const float* __restrict__ pnum,   // [B, HW]
    const float* __restrict__ gnum,   // [B, HW]
    float* __restrict__ ws)
{
    __shared__ int rm_m[20][64];   // per-row selected min (float bits)
    __shared__ int cd_s[20][64];   // per-col min (d2s)
    __shared__ int mx_s[64];       // per-voxel max dist
    __shared__ int bt_s[64];       // per-voxel cmask bits

    const int tid  = threadIdx.x;
    const int lane = tid & 63;     // voxel within tile
    const int w    = tid >> 6;     // wave 0..3
    const int ri   = w >> 1;       // 0..1 -> rows ri*10..+9
    const int cj   = w & 1;        // 0..1 -> cols cj*10..+9
    const int i0   = ri * 10, j0 = cj * 10;
    const int k    = blockIdx.x * 64 + lane;
    const int b    = k >> 14;
    const int hw   = k & (HW - 1);
    const size_t pb = (size_t)b * 60 * HW + hw;
    const size_t cb = (size_t)b * 20 * HW + hw;

    // ---- independent coalesced loads up-front (256B per wave-instr)
    float dxv[10], dyv[10], dzv[10];
    #pragma unroll
    for (int jj = 0; jj < 10; ++jj) {
        dxv[jj] = gt[pb + (size_t)(3 * (j0 + jj)    ) * HW];
        dyv[jj] = gt[pb + (size_t)(3 * (j0 + jj) + 1) * HW];
        dzv[jj] = gt[pb + (size_t)(3 * (j0 + jj) + 2) * HW];
    }
    unsigned mybits = 0u;          // local bits jj (consume cmask immediately)
    #pragma unroll
    for (int jj = 0; jj < 10; ++jj)
        if (cmask[cb + (size_t)(j0 + jj) * HW] > 0.f) mybits |= 1u << jj;
    float vw = 0.f, pn = 0.f, gn = 0.f;
    if (w == 0) { vw = vmask[k]; pn = pnum[k]; gn = gnum[k]; }

    // ---- init LDS
    {
        int* pm = &rm_m[0][0]; int* pc = &cd_s[0][0];
        #pragma unroll
        for (int q = 0; q < 5; ++q) { pm[tid + q * 256] = INFI; pc[tid + q * 256] = INFI; }
        if (tid < 64) { mx_s[tid] = 0; bt_s[tid] = 0; }
    }
    __syncthreads();

    // ---- publish cmask bits BEFORE the hot loop (ri==0 waves cover all 20 cols)
    if (ri == 0 && mybits) atomicOr(&bt_s[lane], (int)(mybits << j0));
    __syncthreads();

    const unsigned cmbits = (unsigned)bt_s[lane];
    // selected cols for s2d row-min: this wave's masked cols if any masked
    // globally, else all 10 (their min + maxd is exact via vals[1])
    const unsigned sel = cmbits ? ((cmbits >> j0) & 0x3FFu) : 0x3FFu;

    const float INF = __int_as_float(INFI);
    float rmm[10], cds[10], mx = 0.f;
    #pragma unroll
    for (int t = 0; t < 10; ++t) { rmm[t] = INF; cds[t] = INF; }

    #pragma unroll
    for (int r = 0; r < 10; ++r) {
        const int i = i0 + r;
        const float sx = pred[pb + (size_t)(i)      * HW];
        const float sy = pred[pb + (size_t)(20 + i) * HW];
        const float sz = pred[pb + (size_t)(40 + i) * HW];
        #pragma unroll
        for (int jj = 0; jj < 10; ++jj) {
            float d = fabsf(sx - dxv[jj]) + fabsf(sy - dyv[jj]) + fabsf(sz - dzv[jj]);
            mx      = fmaxf(mx, d);
            cds[jj] = fminf(cds[jj], d);
            rmm[r]  = fminf(rmm[r], ((sel >> jj) & 1u) ? d : INF);
        }
    }

    // ---- cross-wave combine: int atomics (values >= 0 -> int order == float order)
    #pragma unroll
    for (int r = 0; r < 10; ++r)
        atomicMin(&rm_m[i0 + r][lane], __float_as_int(rmm[r]));
    #pragma unroll
    for (int jj = 0; jj < 10; ++jj)
        atomicMin(&cd_s[j0 + jj][lane], __float_as_int(cds[jj]));
    atomicMax(&mx_s[lane], __float_as_int(mx));
    __syncthreads();

    // ---- per-tile finalize: wave 0, lane = voxel
    if (w == 0) {
        float srcA = 0.f;
        #pragma unroll
        for (int i = 0; i < 20; ++i) srcA += __int_as_float(rm_m[i][lane]);
        float dsum = 0.f;
        #pragma unroll
        for (int j = 0; j < 20; ++j)
            if ((cmbits >> j) & 1u) dsum += __int_as_float(cd_s[j][lane]);
        const float mxv = __int_as_float(mx_s[lane]);

        float vals[7];
        vals[0] = srcA * vw;                          // src-loss min-sum
        vals[1] = (cmbits == 0u) ? 20.f * vw : 0.f;   // rows needing +max_d
        vals[2] = dsum * vw;                          // dst-loss numerator
        vals[3] = vw * (float)__popc(cmbits);         // dst-loss denominator
        const float diff = pn - gn;
        const float ad = fabsf(diff);
        vals[4] = ((ad < 1.f) ? 0.5f * diff * diff : (ad - 0.5f)) * vw;
        vals[5] = vw;                                 // wsum
        vals[6] = (vw > 0.f) ? mxv : 0.f;             // masked max

        #pragma unroll
        for (int o = 32; o > 0; o >>= 1) {
            #pragma unroll
            for (int x = 0; x < 6; ++x) vals[x] += __shfl_down(vals[x], o);
            vals[6] = fmaxf(vals[6], __shfl_down(vals[6], o));
        }
        if (lane == 0) {
            float* rec = ws + (size_t)blockIdx.x * 8;
            #pragma unroll
            for (int x = 0; x < 7; ++x) rec[x] = vals[x];
        }
    }
}

__global__ __launch_bounds__(256) void chamfer_fin(
    const float* __restrict__ ws, float* __restrict__ out)
{
    __shared__ float red[4][8];
    const int tid  = threadIdx.x;
    const int lane = tid & 63;
    const int wv   = tid >> 6;
    float a[6] = {0.f, 0.f, 0.f, 0.f, 0.f, 0.f};
    float mx = 0.f;
    for (int r = tid; r < NTILES; r += 256) {
        const float* rec = ws + (size_t)r * 8;
        #pragma unroll
        for (int v = 0; v < 6; ++v) a[v] += rec[v];
        mx = fmaxf(mx, rec[6]);
    }
    #pragma unroll
    for (int o = 32; o > 0; o >>= 1) {
        #pragma unroll
        for (int v = 0; v < 6; ++v) a[v] += __shfl_down(a[v], o);
        mx = fmaxf(mx, __shfl_down(mx, o));
    }
    if (lane == 0) {
        #pragma unroll
        for (int v = 0; v < 6; ++v) red[wv][v] = a[v];
        red[wv][6] = mx;
    }
    __syncthreads();
    if (tid == 0) {
        #pragma unroll
        for (int v = 0; v < 6; ++v) a[v] = red[0][v] + red[1][v] + red[2][v] + red[3][v];
        mx = fmaxf(fmaxf(red[0][6], red[1][6]), fmaxf(red[2][6], red[3][6]));
        const float loss_s = (a[0] + a[1] * mx) / (a[5] * 20.f);
        const float loss_d = a[2] / a[3];
        const float numl   = a[4] / a[5];
        out[0] = loss_s + loss_d + 0.1f * numl;
    }
}

extern "C" void kernel_launch(void* const* d_in, const int* in_sizes, int n_in,
                              void* d_out, int out_size, void* d_ws, size_t ws_size,
                              hipStream_t stream)
{
    const float* pred  = (const float*)d_in[0];
    const float* gt    = (const float*)d_in[1];
    const float* cmask = (const float*)d_in[2];
    const float* vmask = (const float*)d_in[3];
    const float* pnum  = (const float*)d_in[4];
    const float* gnum  = (const float*)d_in[5];
    float* out = (float*)d_out;
    float* ws  = (float*)d_ws;

    chamfer_main<<<NTILES, 256, 0, stream>>>(pred, gt, cmask, vmask, pnum, gnum, ws);
    chamfer_fin<<<1, 256, 0, stream>>>(ws, out);
}

// Round 17
// 17.827 us; speedup vs baseline: 1.0851x; 1.0851x over previous
//
#include <hip/hip_runtime.h>
#include <stdint.h>

// Shapes fixed by setup_inputs: B=4, D=20, H=W=128, HW=16384, 1024 tiles of 64 voxels.
// R17 = R15 (proven 17.7us) with launch_bounds(512,8):
//  - R15 vs R16 showed the kernel is TLP/latency-bound: R15's 24 waves/CU beat
//    R16's 16 despite 30% more load instructions. (512,8) caps VGPR at 64;
//    R15's lean body (~45-50 live: gt 15 + rmm 10 + cds 5 + temps) should fit
//    -> 4 blocks/CU = 32 waves/CU (8/SIMD), +33% TLP.
//  - R12's (512,8) spill (VGPR=32, 45MB scratch) was a fatter body (fallback
//    branch + merged reduction). Falsifier for this round: same signature.
//  - All else identical to R15: 8 waves x (10 rows x 5 cols), publish-bits-early,
//    branch-free sel, LDS int-atomic combine, record stores + separate fin.
#define HW     16384
#define NTILES 1024
#define INFI   0x7f800000

__global__ __launch_bounds__(512, 8) void chamfer_main(
    const float* __restrict__ pred,   // [B, 60, HW]  channel c*20+i
    const float* __restrict__ gt,     // [B, 60, HW]  channel j*3+c
    const float* __restrict__ cmask,  // [B, 20, HW]
    const float* __restrict__ vmask,  // [B, HW]
    const float* __restrict__ pnum,   // [B, HW]
    const float* __restrict__ gnum,   // [B, HW]
    float* __restrict__ ws)
{
    __shared__ int rm_m[20][64];   // per-row selected min (float bits)
    __shared__ int cd_s[20][64];   // per-col min (d2s)
    __shared__ int mx_s[64];       // per-voxel max dist
    __shared__ int bt_s[64];       // per-voxel cmask bits

    const int tid  = threadIdx.x;
    const int lane = tid & 63;     // voxel within tile
    const int w    = tid >> 6;     // wave 0..7
    const int ri   = w >> 2;       // 0..1 -> rows i0..i0+9
    const int cj   = w & 3;        // 0..3 -> cols j0..j0+4
    const int i0   = ri * 10, j0 = cj * 5;
    const int k    = blockIdx.x * 64 + lane;
    const int b    = k >> 14;
    const int hw   = k & (HW - 1);
    const size_t pb = (size_t)b * 60 * HW + hw;
    const size_t cb = (size_t)b * 20 * HW + hw;

    // ---- independent coalesced loads up-front (256B per wave-instr)
    float dxv[5], dyv[5], dzv[5], cmf[5];
    #pragma unroll
    for (int jj = 0; jj < 5; ++jj) {
        dxv[jj] = gt[pb + (size_t)(3 * (j0 + jj)    ) * HW];
        dyv[jj] = gt[pb + (size_t)(3 * (j0 + jj) + 1) * HW];
        dzv[jj] = gt[pb + (size_t)(3 * (j0 + jj) + 2) * HW];
        cmf[jj] = cmask[cb + (size_t)(j0 + jj) * HW];
    }
    float vw = 0.f, pn = 0.f, gn = 0.f;
    if (w == 0) { vw = vmask[k]; pn = pnum[k]; gn = gnum[k]; }

    // ---- init LDS while loads are in flight
    {
        int* pm = &rm_m[0][0]; int* pc = &cd_s[0][0];
        #pragma unroll
        for (int q = 0; q < 3; ++q) {
            const int t = tid + q * 512;
            if (t < 1280) { pm[t] = INFI; pc[t] = INFI; }
        }
        if (tid < 64) { mx_s[tid] = 0; bt_s[tid] = 0; }
    }
    __syncthreads();

    // ---- publish cmask bits BEFORE the hot loop (ri==0 waves cover all cols)
    unsigned mybits = 0u;
    #pragma unroll
    for (int jj = 0; jj < 5; ++jj)
        if (cmf[jj] > 0.f) mybits |= 1u << jj;
    if (ri == 0 && mybits) atomicOr(&bt_s[lane], (int)(mybits << j0));
    __syncthreads();

    const unsigned cmbits = (unsigned)bt_s[lane];
    // selected cols for the s2d row-min: masked cols if any masked globally,
    // else all cols (their min + maxd is exact via vals[1])
    const unsigned sel = cmbits ? mybits : 0x1Fu;

    const float INF = __int_as_float(INFI);
    float rmm[10], cds[5], mx = 0.f;
    #pragma unroll
    for (int t = 0; t < 10; ++t) rmm[t] = INF;
    #pragma unroll
    for (int t = 0; t < 5; ++t) cds[t] = INF;

    #pragma unroll
    for (int r = 0; r < 10; ++r) {
        const int i = i0 + r;
        const float sx = pred[pb + (size_t)(i)      * HW];
        const float sy = pred[pb + (size_t)(20 + i) * HW];
        const float sz = pred[pb + (size_t)(40 + i) * HW];
        #pragma unroll
        for (int jj = 0; jj < 5; ++jj) {
            float d = fabsf(sx - dxv[jj]) + fabsf(sy - dyv[jj]) + fabsf(sz - dzv[jj]);
            mx      = fmaxf(mx, d);
            cds[jj] = fminf(cds[jj], d);
            rmm[r]  = fminf(rmm[r], ((sel >> jj) & 1u) ? d : INF);
        }
    }

    // ---- cross-wave combine: int atomics (all values >= 0 -> int order == float order)
    #pragma unroll
    for (int r = 0; r < 10; ++r)
        atomicMin(&rm_m[i0 + r][lane], __float_as_int(rmm[r]));
    #pragma unroll
    for (int jj = 0; jj < 5; ++jj)
        atomicMin(&cd_s[j0 + jj][lane], __float_as_int(cds[jj]));
    atomicMax(&mx_s[lane], __float_as_int(mx));
    __syncthreads();

    // ---- per-tile finalize: wave 0, lane = voxel
    if (w == 0) {
        float srcA = 0.f;
        #pragma unroll
        for (int i = 0; i < 20; ++i) srcA += __int_as_float(rm_m[i][lane]);
        float dsum = 0.f;
        #pragma unroll
        for (int j = 0; j < 20; ++j)
            if ((cmbits >> j) & 1u) dsum += __int_as_float(cd_s[j][lane]);
        const float mxv = __int_as_float(mx_s[lane]);

        float vals[7];
        vals[0] = srcA * vw;                          // src-loss min-sum
        vals[1] = (cmbits == 0u) ? 20.f * vw : 0.f;   // rows needing +max_d
        vals[2] = dsum * vw;                          // dst-loss numerator
        vals[3] = vw * (float)__popc(cmbits);         // dst-loss denominator
        const float diff = pn - gn;
        const float ad = fabsf(diff);
        vals[4] = ((ad < 1.f) ? 0.5f * diff * diff : (ad - 0.5f)) * vw;
        vals[5] = vw;                                 // wsum
        vals[6] = (vw > 0.f) ? mxv : 0.f;             // masked max

        #pragma unroll
        for (int o = 32; o > 0; o >>= 1) {
            #pragma unroll
            for (int x = 0; x < 6; ++x) vals[x] += __shfl_down(vals[x], o);
            vals[6] = fmaxf(vals[6], __shfl_down(vals[6], o));
        }
        if (lane == 0) {
            float* rec = ws + (size_t)blockIdx.x * 8;
            #pragma unroll
            for (int x = 0; x < 7; ++x) rec[x] = vals[x];
        }
    }
}

__global__ __launch_bounds__(256) void chamfer_fin(
    const float* __restrict__ ws, float* __restrict__ out)
{
    __shared__ float red[4][8];
    const int tid  = threadIdx.x;
    const int lane = tid & 63;
    const int wv   = tid >> 6;
    float a[6] = {0.f, 0.f, 0.f, 0.f, 0.f, 0.f};
    float mx = 0.f;
    for (int r = tid; r < NTILES; r += 256) {
        const float* rec = ws + (size_t)r * 8;
        #pragma unroll
        for (int v = 0; v < 6; ++v) a[v] += rec[v];
        mx = fmaxf(mx, rec[6]);
    }
    #pragma unroll
    for (int o = 32; o > 0; o >>= 1) {
        #pragma unroll
        for (int v = 0; v < 6; ++v) a[v] += __shfl_down(a[v], o);
        mx = fmaxf(mx, __shfl_down(mx, o));
    }
    if (lane == 0) {
        #pragma unroll
        for (int v = 0; v < 6; ++v) red[wv][v] = a[v];
        red[wv][6] = mx;
    }
    __syncthreads();
    if (tid == 0) {
        #pragma unroll
        for (int v = 0; v < 6; ++v) a[v] = red[0][v] + red[1][v] + red[2][v] + red[3][v];
        mx = fmaxf(fmaxf(red[0][6], red[1][6]), fmaxf(red[2][6], red[3][6]));
        const float loss_s = (a[0] + a[1] * mx) / (a[5] * 20.f);
        const float loss_d = a[2] / a[3];
        const float numl   = a[4] / a[5];
        out[0] = loss_s + loss_d + 0.1f * numl;
    }
}

extern "C" void kernel_launch(void* const* d_in, const int* in_sizes, int n_in,
                              void* d_out, int out_size, void* d_ws, size_t ws_size,
                              hipStream_t stream)
{
    const float* pred  = (const float*)d_in[0];
    const float* gt    = (const float*)d_in[1];
    const float* cmask = (const float*)d_in[2];
    const float* vmask = (const float*)d_in[3];
    const float* pnum  = (const float*)d_in[4];
    const float* gnum  = (const float*)d_in[5];
    float* out = (float*)d_out;
    float* ws  = (float*)d_ws;

    chamfer_main<<<NTILES, 512, 0, stream>>>(pred, gt, cmask, vmask, pnum, gnum, ws);
    chamfer_fin<<<1, 256, 0, stream>>>(ws, out);
}